// Round 7
// baseline (179.052 us; speedup 1.0000x reference)
//
#include <hip/hip_runtime.h>
#include <hip/hip_bf16.h>

// GegenbauerKAN layer == fused BF16-MFMA GEMM, M=16384 N=512 K=4096 (i*8+d).
// ALPHA=1 => Chebyshev-U recurrence: C_{n+1} = 2t*C_n - C_{n-1}, t = tanh(x).
// R2: coeffs pre-converted to bf16 in d_ws (cvt_w).
// R3 (REVERTED): explicit dbuf -6%. R4: 4 blk/CU + cvt_pk (100us).
// R5: K-split waves (94us). R6: BN=256 flat. R7 (REVERTED): reg-direct but
//     1 wave/SIMD -> latency-bound 144us. R8: reg-features + direct-B +
//     K-split TLP (2 waves/SIMD) -> 81us, MfmaUtil 36.
// R9: kill the main-loop LDS restage + its lgkmcnt/sched_barrier fences
//     (they serialized each iter and blocked cross-iter compiler pipelining).
//     A-path = R7's direct per-lane gather (8 scalars; wave touches 16 rows
//     x 16B contiguous per instr, L2-resident). Depth-1 x prefetch (xn) so
//     next iter's gathers fly under this iter's MFMA wall. Feature VALU
//     split between the two MFMA half-blocks for issue-slot interleave.
//     setprio(1) around MFMA clusters (independent waves, attn-like regime).
//     MFMA floor 27.5us; target window max(MFMA, VALU) ~= 2100-2500cy/SIMD-iter.

#define I_DIM 512
#define O_DIM 512
#define NDEG 8
#define KH_ITERS 32            // 32 i-octets per K-half wave
#define W_ELEMS (I_DIM * O_DIM * NDEG)   // 2,097,152

typedef __attribute__((ext_vector_type(8))) short s8v;    // MFMA A/B frag (8 bf16)
typedef __attribute__((ext_vector_type(4))) float f32x4;  // MFMA C/D frag
typedef unsigned short u16;

// HW packed f32->bf16 (RNE): D[15:0]=bf16(lo), D[31:16]=bf16(hi). 1 VALU op.
__device__ __forceinline__ unsigned cvt_pk_bf16(float lo, float hi) {
    unsigned r;
    asm("v_cvt_pk_bf16_f32 %0, %1, %2" : "=v"(r) : "v"(lo), "v"(hi));
    return r;
}

__device__ __forceinline__ float fast_tanh(float v) {
    float e = __expf(v + v);
    float r = __builtin_amdgcn_rcpf(e + 1.0f);
    return 1.0f - (r + r);
}

// Build the A-fragment (8 Chebyshev-U features of one x value) in registers.
__device__ __forceinline__ s8v feat_frag(float xv) {
    const float t  = fast_tanh(xv);
    const float t2 = t + t;
    const float c1 = t2;
    const float c2 = t2 * c1 - 1.0f;
    const float c3 = t2 * c2 - c1;
    const float c4 = t2 * c3 - c2;
    const float c5 = t2 * c4 - c3;
    const float c6 = t2 * c5 - c4;
    const float c7 = t2 * c6 - c5;
    union { s8v s; unsigned u[4]; } pk;
    pk.u[0] = cvt_pk_bf16(1.0f, c1);
    pk.u[1] = cvt_pk_bf16(c2, c3);
    pk.u[2] = cvt_pk_bf16(c4, c5);
    pk.u[3] = cvt_pk_bf16(c6, c7);
    return pk.s;
}

// ---- one-shot coeffs fp32 -> bf16 into workspace (re-run every call; ws is re-poisoned)
extern "C" __global__ __launch_bounds__(256)
void cvt_w(const float* __restrict__ cf, u16* __restrict__ wbf) {
    const size_t idx = ((size_t)blockIdx.x * 256 + threadIdx.x) * 4;
    const float4 v = *reinterpret_cast<const float4*>(cf + idx);
    unsigned* dst = reinterpret_cast<unsigned*>(wbf + idx);
    dst[0] = cvt_pk_bf16(v.x, v.y);
    dst[1] = cvt_pk_bf16(v.z, v.w);
}

template <bool PRECONV>
__global__ __launch_bounds__(256, 2)
void gegen_gemm(const float* __restrict__ x,
                const float* __restrict__ cf,
                const u16* __restrict__ wbf,
                float* __restrict__ out)
{
    __shared__ float smem[4096];           // epilogue K-half reduce only (16 KB)

    const int tid  = threadIdx.x;
    const int lane = tid & 63;
    const int wave = tid >> 6;             // 0..3
    const int m4   = wave & 1;             // M-slice (64 rows)
    const int kh   = wave >> 1;            // K-half
    const int fm   = lane & 15;
    const int fq   = lane >> 4;

    const int bm0 = blockIdx.x * 128 + m4 * 64;   // wave's M base
    const int bn0 = blockIdx.y * 128;             // block's N base
    const int kbase = kh * (KH_ITERS * 8);        // starting i for this K-half

    // gather bases: elements (fq) and (fq+4) of rows bm0 + tm*16 + fm
    const float* xg0 = x + (size_t)(bm0 +  0 + fm) * I_DIM + kbase + fq;
    const float* xg1 = x + (size_t)(bm0 + 16 + fm) * I_DIM + kbase + fq;
    const float* xg2 = x + (size_t)(bm0 + 32 + fm) * I_DIM + kbase + fq;
    const float* xg3 = x + (size_t)(bm0 + 48 + fm) * I_DIM + kbase + fq;

    f32x4 acc[4][8];
#pragma unroll
    for (int a = 0; a < 4; ++a)
#pragma unroll
        for (int b = 0; b < 8; ++b)
            acc[a][b] = (f32x4){0.0f, 0.0f, 0.0f, 0.0f};

    // prologue: gather iter 0's 8 x scalars
    float xc[8], xn[8];
    xc[0] = xg0[0]; xc[1] = xg0[4];
    xc[2] = xg1[0]; xc[3] = xg1[4];
    xc[4] = xg2[0]; xc[5] = xg2[4];
    xc[6] = xg3[0]; xc[7] = xg3[4];

    for (int it = 0; it < KH_ITERS; ++it) {
        const int g8 = kbase + it * 8;

        // ---- B frags: direct from global (L2-resident W), 16B each,
        //      tn offsets fold into the 13-bit imm (tn*256B) ----
        s8v bfr0[8], bfr1[8];
        if (PRECONV) {
            const u16* wb0 = wbf + ((size_t)(g8 + fq) * O_DIM + bn0 + fm) * NDEG;
            const u16* wb1 = wb0 + (size_t)4 * O_DIM * NDEG;   // i += 4
#pragma unroll
            for (int tn = 0; tn < 8; ++tn)
                bfr0[tn] = *reinterpret_cast<const s8v*>(wb0 + tn * 16 * NDEG);
#pragma unroll
            for (int tn = 0; tn < 8; ++tn)
                bfr1[tn] = *reinterpret_cast<const s8v*>(wb1 + tn * 16 * NDEG);
        } else {
            const float* wb0 = cf + ((size_t)(g8 + fq) * O_DIM + bn0 + fm) * NDEG;
            const float* wb1 = wb0 + (size_t)4 * O_DIM * NDEG;
#pragma unroll
            for (int tn = 0; tn < 8; ++tn) {
                const float4 w0 = reinterpret_cast<const float4*>(wb0 + tn * 16 * NDEG)[0];
                const float4 w1 = reinterpret_cast<const float4*>(wb0 + tn * 16 * NDEG)[1];
                union { s8v s; unsigned u[4]; } pk;
                pk.u[0] = cvt_pk_bf16(w0.x, w0.y);
                pk.u[1] = cvt_pk_bf16(w0.z, w0.w);
                pk.u[2] = cvt_pk_bf16(w1.x, w1.y);
                pk.u[3] = cvt_pk_bf16(w1.z, w1.w);
                bfr0[tn] = pk.s;
            }
#pragma unroll
            for (int tn = 0; tn < 8; ++tn) {
                const float4 w0 = reinterpret_cast<const float4*>(wb1 + tn * 16 * NDEG)[0];
                const float4 w1 = reinterpret_cast<const float4*>(wb1 + tn * 16 * NDEG)[1];
                union { s8v s; unsigned u[4]; } pk;
                pk.u[0] = cvt_pk_bf16(w0.x, w0.y);
                pk.u[1] = cvt_pk_bf16(w0.z, w0.w);
                pk.u[2] = cvt_pk_bf16(w1.x, w1.y);
                pk.u[3] = cvt_pk_bf16(w1.z, w1.w);
                bfr1[tn] = pk.s;
            }
        }

        // ---- prefetch next iter's x (clamped last iter; values discarded) ----
        const int off = (it + 1 < KH_ITERS ? it + 1 : it) * 8;
        xn[0] = xg0[off]; xn[1] = xg0[off + 4];
        xn[2] = xg1[off]; xn[3] = xg1[off + 4];
        xn[4] = xg2[off]; xn[5] = xg2[off + 4];
        xn[6] = xg3[off]; xn[7] = xg3[off + 4];

        // ---- features (kc=0) while B-loads fly, then MFMA half-block ----
        s8v afr[4];
        afr[0] = feat_frag(xc[0]);
        afr[1] = feat_frag(xc[2]);
        afr[2] = feat_frag(xc[4]);
        afr[3] = feat_frag(xc[6]);
        __builtin_amdgcn_s_setprio(1);
#pragma unroll
        for (int tm = 0; tm < 4; ++tm)
#pragma unroll
            for (int tn = 0; tn < 8; ++tn)
                acc[tm][tn] = __builtin_amdgcn_mfma_f32_16x16x32_bf16(
                    afr[tm], bfr0[tn], acc[tm][tn], 0, 0, 0);
        __builtin_amdgcn_s_setprio(0);

        // ---- features (kc=1) interleave into MFMA issue gaps, then half-block ----
        afr[0] = feat_frag(xc[1]);
        afr[1] = feat_frag(xc[3]);
        afr[2] = feat_frag(xc[5]);
        afr[3] = feat_frag(xc[7]);
        __builtin_amdgcn_s_setprio(1);
#pragma unroll
        for (int tm = 0; tm < 4; ++tm)
#pragma unroll
            for (int tn = 0; tn < 8; ++tn)
                acc[tm][tn] = __builtin_amdgcn_mfma_f32_16x16x32_bf16(
                    afr[tm], bfr1[tn], acc[tm][tn], 0, 0, 0);
        __builtin_amdgcn_s_setprio(0);

        // rotate prefetch
#pragma unroll
        for (int e = 0; e < 8; ++e) xc[e] = xn[e];
    }

    // ---- epilogue: K-half pair-reduction via LDS, chunked by tm ----
    // C/D frag: col=fm, row=fq*4+r within 16x16 tile (tm*16, tn*16).
#pragma unroll
    for (int tm = 0; tm < 4; ++tm) {
        if (kh == 1) {
#pragma unroll
            for (int tn = 0; tn < 8; ++tn)
#pragma unroll
                for (int r = 0; r < 4; ++r)
                    smem[m4 * 2048 + (fq * 4 + r) * 128 + tn * 16 + fm] = acc[tm][tn][r];
        }
        __syncthreads();
        if (kh == 0) {
#pragma unroll
            for (int tn = 0; tn < 8; ++tn) {
                const int row = bm0 + tm * 16 + fq * 4;
                const int col = bn0 + tn * 16 + fm;
#pragma unroll
                for (int r = 0; r < 4; ++r)
                    out[(size_t)(row + r) * O_DIM + col] =
                        acc[tm][tn][r] + smem[m4 * 2048 + (fq * 4 + r) * 128 + tn * 16 + fm];
            }
        }
        __syncthreads();   // smem reused next tm chunk
    }
}

extern "C" void kernel_launch(void* const* d_in, const int* in_sizes, int n_in,
                              void* d_out, int out_size, void* d_ws, size_t ws_size,
                              hipStream_t stream) {
    const float* x  = (const float*)d_in[0];
    const float* cf = (const float*)d_in[1];
    float* out = (float*)d_out;
    const int M = in_sizes[0] / I_DIM;            // 16384
    dim3 grid(M / 128, O_DIM / 128);              // (128, 4) = 512 blocks = 2/CU
    dim3 block(256, 1, 1);

    if (ws_size >= (size_t)W_ELEMS * sizeof(u16)) {
        u16* wbf = (u16*)d_ws;
        cvt_w<<<W_ELEMS / 1024, 256, 0, stream>>>(cf, wbf);
        gegen_gemm<true><<<grid, block, 0, stream>>>(x, cf, wbf, out);
    } else {
        gegen_gemm<false><<<grid, block, 0, stream>>>(x, cf, nullptr, out);
    }
}

// Round 8
// 153.927 us; speedup vs baseline: 1.1632x; 1.1632x over previous
//
#include <hip/hip_runtime.h>
#include <hip/hip_bf16.h>

// GegenbauerKAN layer == fused BF16-MFMA GEMM, M=16384 N=512 K=4096 (i*8+d).
// ALPHA=1 => Chebyshev-U recurrence: C_{n+1} = 2t*C_n - C_{n-1}, t = tanh(x).
// R2: coeffs pre-converted to bf16 in d_ws (cvt_w).
// R3 (REVERTED): explicit dbuf -6%. R4: 4 blk/CU + cvt_pk (100us).
// R5: K-split waves (94us). R6: BN=256 flat. R7 (REVERTED): reg-direct,
//     1 wave/SIMD, latency-bound 144us. R8: reg-features + direct-B +
//     K-split TLP -> 81us, MfmaUtil 36. R9 (REVERTED): per-lane x gather
//     (8 strided scalar loads) regressed to 112us — restage via coalesced
//     dwordx4 + LDS is the right A-path.
// R10: R8 with the restage PIPELINED across iterations:
//     - ds_write of x[it+1] moved to iter BOTTOM (after MFMA wall; its
//       global load has landed -> no vmcnt stall in the chain).
//     - lgkmcnt(0) fence at iter TOP waits on a write issued ~2000cy ago
//       (free). Per-iter chain is now just ds_read -> features -> MFMA.
//     - B-frags + x[it+1] issued at iter top, covered by feature VALU.
//     - setprio(1) around MFMA clusters (independent waves, no barriers).

#define I_DIM 512
#define O_DIM 512
#define NDEG 8
#define KH_ITERS 32            // 32 i-octets per K-half wave
#define W_ELEMS (I_DIM * O_DIM * NDEG)   // 2,097,152

typedef __attribute__((ext_vector_type(8))) short s8v;    // MFMA A/B frag (8 bf16)
typedef __attribute__((ext_vector_type(4))) float f32x4;  // MFMA C/D frag
typedef unsigned short u16;

// HW packed f32->bf16 (RNE): D[15:0]=bf16(lo), D[31:16]=bf16(hi). 1 VALU op.
__device__ __forceinline__ unsigned cvt_pk_bf16(float lo, float hi) {
    unsigned r;
    asm("v_cvt_pk_bf16_f32 %0, %1, %2" : "=v"(r) : "v"(lo), "v"(hi));
    return r;
}

__device__ __forceinline__ float fast_tanh(float v) {
    float e = __expf(v + v);
    float r = __builtin_amdgcn_rcpf(e + 1.0f);
    return 1.0f - (r + r);
}

// Build the A-fragment (8 Chebyshev-U features of one x value) in registers.
__device__ __forceinline__ s8v feat_frag(float xv) {
    const float t  = fast_tanh(xv);
    const float t2 = t + t;
    const float c1 = t2;
    const float c2 = t2 * c1 - 1.0f;
    const float c3 = t2 * c2 - c1;
    const float c4 = t2 * c3 - c2;
    const float c5 = t2 * c4 - c3;
    const float c6 = t2 * c5 - c4;
    const float c7 = t2 * c6 - c5;
    union { s8v s; unsigned u[4]; } pk;
    pk.u[0] = cvt_pk_bf16(1.0f, c1);
    pk.u[1] = cvt_pk_bf16(c2, c3);
    pk.u[2] = cvt_pk_bf16(c4, c5);
    pk.u[3] = cvt_pk_bf16(c6, c7);
    return pk.s;
}

// ---- one-shot coeffs fp32 -> bf16 into workspace (re-run every call; ws is re-poisoned)
extern "C" __global__ __launch_bounds__(256)
void cvt_w(const float* __restrict__ cf, u16* __restrict__ wbf) {
    const size_t idx = ((size_t)blockIdx.x * 256 + threadIdx.x) * 4;
    const float4 v = *reinterpret_cast<const float4*>(cf + idx);
    unsigned* dst = reinterpret_cast<unsigned*>(wbf + idx);
    dst[0] = cvt_pk_bf16(v.x, v.y);
    dst[1] = cvt_pk_bf16(v.z, v.w);
}

template <bool PRECONV>
__global__ __launch_bounds__(256, 2)
void gegen_gemm(const float* __restrict__ x,
                const float* __restrict__ cf,
                const u16* __restrict__ wbf,
                float* __restrict__ out)
{
    // 16KB union: main loop = per-wave x slots [wave][buf(512 floats)][64][8];
    //             epilogue  = K-half reduce buffer [m4][16][128].
    __shared__ float smem[4096];

    const int tid  = threadIdx.x;
    const int lane = tid & 63;
    const int wave = tid >> 6;             // 0..3
    const int m4   = wave & 1;             // M-slice (64 rows)
    const int kh   = wave >> 1;            // K-half
    const int fm   = lane & 15;
    const int fq   = lane >> 4;

    const int bm0 = blockIdx.x * 128 + m4 * 64;   // wave's M base
    const int bn0 = blockIdx.y * 128;             // block's N base
    const int kbase = kh * (KH_ITERS * 8);        // starting i for this K-half

    // x staging: lane owns row (bm0 + lane)
    const float* xrow = x + (size_t)(bm0 + lane) * I_DIM + kbase;
    float* xslot = &smem[wave * 1024];            // [buf(512)][lane*8]

    f32x4 acc[4][8];
#pragma unroll
    for (int a = 0; a < 4; ++a)
#pragma unroll
        for (int b = 0; b < 8; ++b)
            acc[a][b] = (f32x4){0.0f, 0.0f, 0.0f, 0.0f};

    // ---- prologue: stage iter 0's x into slot buf 0 ----
    {
        const float4 xa = *reinterpret_cast<const float4*>(xrow);
        const float4 xb = *reinterpret_cast<const float4*>(xrow + 4);
        *reinterpret_cast<f32x4*>(&xslot[lane * 8])     = (f32x4){xa.x, xa.y, xa.z, xa.w};
        *reinterpret_cast<f32x4*>(&xslot[lane * 8 + 4]) = (f32x4){xb.x, xb.y, xb.z, xb.w};
    }

    for (int it = 0; it < KH_ITERS; ++it) {
        const int g8   = kbase + it * 8;
        const int buf  = (it & 1) * 512;
        const int nbuf = buf ^ 512;

        // ---- B frags: issue direct from global (L2-resident W), 16B each ----
        s8v bfr0[8], bfr1[8];
        if (PRECONV) {
            const u16* wb0 = wbf + ((size_t)(g8 + fq) * O_DIM + bn0 + fm) * NDEG;
            const u16* wb1 = wb0 + (size_t)4 * O_DIM * NDEG;   // i += 4
#pragma unroll
            for (int tn = 0; tn < 8; ++tn)
                bfr0[tn] = *reinterpret_cast<const s8v*>(wb0 + tn * 16 * NDEG);
#pragma unroll
            for (int tn = 0; tn < 8; ++tn)
                bfr1[tn] = *reinterpret_cast<const s8v*>(wb1 + tn * 16 * NDEG);
        } else {
            const float* wb0 = cf + ((size_t)(g8 + fq) * O_DIM + bn0 + fm) * NDEG;
            const float* wb1 = wb0 + (size_t)4 * O_DIM * NDEG;
#pragma unroll
            for (int tn = 0; tn < 8; ++tn) {
                const float4 w0 = reinterpret_cast<const float4*>(wb0 + tn * 16 * NDEG)[0];
                const float4 w1 = reinterpret_cast<const float4*>(wb0 + tn * 16 * NDEG)[1];
                union { s8v s; unsigned u[4]; } pk;
                pk.u[0] = cvt_pk_bf16(w0.x, w0.y);
                pk.u[1] = cvt_pk_bf16(w0.z, w0.w);
                pk.u[2] = cvt_pk_bf16(w1.x, w1.y);
                pk.u[3] = cvt_pk_bf16(w1.z, w1.w);
                bfr0[tn] = pk.s;
            }
#pragma unroll
            for (int tn = 0; tn < 8; ++tn) {
                const float4 w0 = reinterpret_cast<const float4*>(wb1 + tn * 16 * NDEG)[0];
                const float4 w1 = reinterpret_cast<const float4*>(wb1 + tn * 16 * NDEG)[1];
                union { s8v s; unsigned u[4]; } pk;
                pk.u[0] = cvt_pk_bf16(w0.x, w0.y);
                pk.u[1] = cvt_pk_bf16(w0.z, w0.w);
                pk.u[2] = cvt_pk_bf16(w1.x, w1.y);
                pk.u[3] = cvt_pk_bf16(w1.z, w1.w);
                bfr1[tn] = pk.s;
            }
        }

        // ---- issue next iter's x load (lands during this iter's MFMA wall) ----
        float4 xa2, xb2;
        const bool more = (it + 1 < KH_ITERS);
        if (more) {
            xa2 = *reinterpret_cast<const float4*>(xrow + (it + 1) * 8);
            xb2 = *reinterpret_cast<const float4*>(xrow + (it + 1) * 8 + 4);
        }

        // ---- fence: prev iter's (or prologue's) ds_write completed long ago ----
        asm volatile("s_waitcnt lgkmcnt(0)" ::: "memory");

        // ---- read this lane's 8 scalars; features in registers ----
        s8v afr[4];
#pragma unroll
        for (int tm = 0; tm < 4; ++tm)
            afr[tm] = feat_frag(xslot[buf + (tm * 16 + fm) * 8 + fq]);        // kc=0

        __builtin_amdgcn_s_setprio(1);
#pragma unroll
        for (int tm = 0; tm < 4; ++tm)
#pragma unroll
            for (int tn = 0; tn < 8; ++tn)
                acc[tm][tn] = __builtin_amdgcn_mfma_f32_16x16x32_bf16(
                    afr[tm], bfr0[tn], acc[tm][tn], 0, 0, 0);
        __builtin_amdgcn_s_setprio(0);

#pragma unroll
        for (int tm = 0; tm < 4; ++tm)
            afr[tm] = feat_frag(xslot[buf + (tm * 16 + fm) * 8 + 4 + fq]);    // kc=1

        __builtin_amdgcn_s_setprio(1);
#pragma unroll
        for (int tm = 0; tm < 4; ++tm)
#pragma unroll
            for (int tn = 0; tn < 8; ++tn)
                acc[tm][tn] = __builtin_amdgcn_mfma_f32_16x16x32_bf16(
                    afr[tm], bfr1[tn], acc[tm][tn], 0, 0, 0);
        __builtin_amdgcn_s_setprio(0);

        // ---- write-ahead: stage x[it+1] into the other slot (x loads landed) ----
        if (more) {
            *reinterpret_cast<f32x4*>(&xslot[nbuf + lane * 8])     = (f32x4){xa2.x, xa2.y, xa2.z, xa2.w};
            *reinterpret_cast<f32x4*>(&xslot[nbuf + lane * 8 + 4]) = (f32x4){xb2.x, xb2.y, xb2.z, xb2.w};
        }
    }

    // ---- epilogue: K-half pair-reduction via LDS, chunked by tm ----
    // C/D frag: col=fm, row=fq*4+r within 16x16 tile (tm*16, tn*16).
    __syncthreads();   // x slots done block-wide; smem becomes reduce buffer
#pragma unroll
    for (int tm = 0; tm < 4; ++tm) {
        if (kh == 1) {
#pragma unroll
            for (int tn = 0; tn < 8; ++tn)
#pragma unroll
                for (int r = 0; r < 4; ++r)
                    smem[m4 * 2048 + (fq * 4 + r) * 128 + tn * 16 + fm] = acc[tm][tn][r];
        }
        __syncthreads();
        if (kh == 0) {
#pragma unroll
            for (int tn = 0; tn < 8; ++tn) {
                const int row = bm0 + tm * 16 + fq * 4;
                const int col = bn0 + tn * 16 + fm;
#pragma unroll
                for (int r = 0; r < 4; ++r)
                    out[(size_t)(row + r) * O_DIM + col] =
                        acc[tm][tn][r] + smem[m4 * 2048 + (fq * 4 + r) * 128 + tn * 16 + fm];
            }
        }
        __syncthreads();   // smem reused next tm chunk
    }
}

extern "C" void kernel_launch(void* const* d_in, const int* in_sizes, int n_in,
                              void* d_out, int out_size, void* d_ws, size_t ws_size,
                              hipStream_t stream) {
    const float* x  = (const float*)d_in[0];
    const float* cf = (const float*)d_in[1];
    float* out = (float*)d_out;
    const int M = in_sizes[0] / I_DIM;            // 16384
    dim3 grid(M / 128, O_DIM / 128);              // (128, 4) = 512 blocks = 2/CU
    dim3 block(256, 1, 1);

    if (ws_size >= (size_t)W_ELEMS * sizeof(u16)) {
        u16* wbf = (u16*)d_ws;
        cvt_w<<<W_ELEMS / 1024, 256, 0, stream>>>(cf, wbf);
        gegen_gemm<true><<<grid, block, 0, stream>>>(x, cf, wbf, out);
    } else {
        gegen_gemm<false><<<grid, block, 0, stream>>>(x, cf, nullptr, out);
    }
}